// Round 6
// baseline (281.902 us; speedup 1.0000x reference)
//
#include <hip/hip_runtime.h>

#define NB 16
#define NC 8
#define HW (512 * 512)
#define TPB 512                       // 8 waves; wave w <-> channel w
#define BLOCKS_PER_B 64
#define NBLOCKS (BLOCKS_PER_B * NB)   // 1024 = exactly 4 blocks/CU at 8 waves/SIMD
#define GPB 1024                      // float4-groups per block per channel
#define ITERS (GPB / 64)              // 16

// ws layout (floats): [0,1024)      S[b][ci][ck]
//                     [1024,1152)   n[b][ck]
//                     [1152]        ce_sum
//                     [1153]        block-done counter (uint32)
#define N_BASE (NB * NC * NC)
#define CE_IDX (NB * NC * NC + NB * NC)
#define CTR_IDX (CE_IDX + 1)
#define WS_FLOATS (CTR_IDX + 1)

__device__ __forceinline__ float wave_reduce(float v) {
#pragma unroll
  for (int off = 32; off > 0; off >>= 1) v += __shfl_xor(v, off, 64);
  return v;
}

// Channel-per-wave: per-thread state ~50 VGPR (S[8] row, not S[8][8]) so we
// run 8 waves/SIMD. Round-3/5 evidence: the S[64]-per-thread variants were
// stuck at <=8 waves/CU and latency-bound (r5: VGPR=128, 10.5% HBM, 13% VALU).
__global__ __launch_bounds__(TPB, 8)
void jce_main(const float* __restrict__ pred, const int* __restrict__ target,
              float* __restrict__ ws, float* __restrict__ out) {
  const int b = blockIdx.y;
  const int tid = threadIdx.x;
  const int w = tid >> 6;    // wave index == channel
  const int lane = tid & 63;

  const float* predc = pred + ((size_t)b * NC + w) * HW;
  const int* tgtb = target + (size_t)b * HW;
  const int g0 = blockIdx.x * GPB;

  // e_tile[c][pix]: phase-1 ds_write_b128 dense; phase-2 reads at c*256+p
  // have bank = p%32 (256%32==0) -> conflict-free even for runtime tc.
  __shared__ __align__(16) float e_tile[NC][256];

  float S[NC], cnt[NC], ce = 0.0f;
#pragma unroll
  for (int k = 0; k < NC; ++k) { S[k] = 0.0f; cnt[k] = 0.0f; }

  for (int it = 0; it < ITERS; ++it) {
    const int g = g0 + it * 64 + lane;
    const int4 t4 = ((const int4*)tgtb)[g];       // all 8 waves: L1 broadcast
    const float4 p4 = ((const float4*)predc)[g];  // wave's own channel stream

    float4 e4;
    e4.x = __expf(p4.x); e4.y = __expf(p4.y);
    e4.z = __expf(p4.z); e4.w = __expf(p4.w);
    ((float4*)&e_tile[w][0])[lane] = e4;          // e_tile[w][4*lane .. +3]

#pragma unroll
    for (int j = 0; j < 4; ++j) {
      const int tc = (j == 0) ? t4.x : (j == 1) ? t4.y : (j == 2) ? t4.z : t4.w;
      const float pv = (j == 0) ? p4.x : (j == 1) ? p4.y : (j == 2) ? p4.z : p4.w;
#pragma unroll
      for (int k = 0; k < NC; ++k) S[k] += (tc == k) ? pv : 0.0f;
      if (w == 0) {
#pragma unroll
        for (int k = 0; k < NC; ++k) cnt[k] += (tc == k) ? 1.0f : 0.0f;
      }
    }
    __syncthreads();

    // phase 2: CE for this iteration's 256-pixel tile (waves 0..3)
    if (tid < 256) {
      const int tc = tgtb[g0 * 4 + it * 256 + tid];   // L1 hit
      float s = 0.0f;
#pragma unroll
      for (int c = 0; c < NC; ++c) s += e_tile[c][tid];
      // p[tc] = log(exp(p[tc])): double-rounding ~1e-6, tolerance 0.825
      ce += __logf(s) - __logf(e_tile[tc][tid]);
    }
    __syncthreads();
  }

  // ---- reductions: butterfly within wave, lane 0 atomics to ws ----
#pragma unroll
  for (int k = 0; k < NC; ++k) S[k] = wave_reduce(S[k]);
  if (w == 0) {
#pragma unroll
    for (int k = 0; k < NC; ++k) cnt[k] = wave_reduce(cnt[k]);
  }
  ce = wave_reduce(ce);  // waves 4..7 contribute 0

  if (lane == 0) {
#pragma unroll
    for (int k = 0; k < NC; ++k)
      atomicAdd(&ws[b * (NC * NC) + w * NC + k], S[k]);
    if (w == 0) {
#pragma unroll
      for (int k = 0; k < NC; ++k)
        atomicAdd(&ws[N_BASE + b * NC + k], cnt[k]);
    }
    if (w < 4) atomicAdd(&ws[CE_IDX], ce);
  }

  // ---- last-block-done finalize ----
  __shared__ int is_last;
  __syncthreads();
  if (tid == 0) {
    __threadfence();
    unsigned prev = atomicAdd((unsigned*)&ws[CTR_IDX], 1u);
    is_last = (prev == (unsigned)(NBLOCKS - 1)) ? 1 : 0;
  }
  __syncthreads();
  if (!is_last) return;

  // Read partials with atomicAdd(p, 0.0f): device-coherent across XCD L2s.
  float acc = 0.0f;
  for (int idx = tid; idx < NB * NC * NC; idx += TPB) {
    const int bb = idx >> 6, ci = (idx >> 3) & 7, ck = idx & 7;
    if (ci == ck) continue;
    const float n_ck = atomicAdd(&ws[N_BASE + bb * NC + ck], 0.0f);
    const float n_ci = atomicAdd(&ws[N_BASE + bb * NC + ci], 0.0f);
    const float Sik = atomicAdd(&ws[bb * (NC * NC) + ci * NC + ck], 0.0f);
    const float Sii = atomicAdd(&ws[bb * (NC * NC) + ci * NC + ci], 0.0f);
    acc += logf(0.5f + 0.5f * (Sii / n_ci - Sik / n_ck));
  }
  acc = wave_reduce(acc);
  __shared__ float red2[TPB / 64];
  if (lane == 0) red2[w] = acc;
  __syncthreads();
  if (tid == 0) {
    float tot = 0.0f;
#pragma unroll
    for (int ww = 0; ww < TPB / 64; ++ww) tot += red2[ww];
    const float jl = -tot / (float)NB;
    const float cesum = atomicAdd(&ws[CE_IDX], 0.0f);
    out[0] = jl + cesum / ((float)NB * (float)HW);
  }
}

extern "C" void kernel_launch(void* const* d_in, const int* in_sizes, int n_in,
                              void* d_out, int out_size, void* d_ws, size_t ws_size,
                              hipStream_t stream) {
  const float* pred = (const float*)d_in[0];
  const int* target = (const int*)d_in[1];
  float* out = (float*)d_out;
  float* ws = (float*)d_ws;

  hipMemsetAsync(ws, 0, WS_FLOATS * sizeof(float), stream);
  dim3 grid(BLOCKS_PER_B, NB);
  jce_main<<<grid, TPB, 0, stream>>>(pred, target, ws, out);
}

// Round 7
// 273.238 us; speedup vs baseline: 1.0317x; 1.0317x over previous
//
#include <hip/hip_runtime.h>

#define NB 16
#define NC 8
#define HW (512 * 512)
#define GRP (HW / 4)      // 65536 float4-groups per (b,c) plane
#define TPB 256
#define PCH_S 16          // S-kernel: grid (16, 8, 16) = 2048 blocks, 16 iters/thread
#define PCH_L 64          // LSE-kernel: grid (64, 16) = 1024 blocks, 4 iters/thread
#define NBLK_L (PCH_L * NB)

// ws (floats): [0,1024) S[b][ci][ck]; [1024,1152) n[b][k]; [1152] lse_sum; [1153] ctr
#define N_BASE (NB * NC * NC)
#define LSE_IDX (N_BASE + NB * NC)
#define CTR_IDX (LSE_IDX + 1)
#define WS_FLOATS (CTR_IDX + 1)

__device__ __forceinline__ float wave_reduce(float v) {
#pragma unroll
  for (int off = 32; off > 0; off >>= 1) v += __shfl_xor(v, off, 64);
  return v;
}

// Block owns (pixel-chunk, channel ci, batch b). Per-thread state ~40 VGPR
// (S_row[8] + cnt[8]) -> 8 waves/SIMD, 2048 blocks = exactly 8 blocks/CU.
// Barrier-free main loop, 2 loads in flight/thread, 32 waves/CU doing TLP.
// r3-r6 lesson: S[8][8]/thread spills or caps occupancy; LDS exchange
// adds barriers. This shape has neither.
__global__ __launch_bounds__(TPB, 8)
void s_kernel(const float* __restrict__ pred, const int* __restrict__ target,
              float* __restrict__ ws) {
  const int px = blockIdx.x, ci = blockIdx.y, b = blockIdx.z;
  const int tid = threadIdx.x;
  const float4* predc = (const float4*)(pred + ((size_t)b * NC + ci) * HW);
  const int4* tgt = (const int4*)(target + (size_t)b * HW);
  const bool do_cnt = (ci == 0);

  float S[NC], cnt[NC];
#pragma unroll
  for (int k = 0; k < NC; ++k) { S[k] = 0.0f; cnt[k] = 0.0f; }

  for (int g = px * TPB + tid; g < GRP; g += PCH_S * TPB) {
    const int4 t4 = tgt[g];
    const float4 p4 = predc[g];
#pragma unroll
    for (int j = 0; j < 4; ++j) {
      const int tc = (j == 0) ? t4.x : (j == 1) ? t4.y : (j == 2) ? t4.z : t4.w;
      const float pv = (j == 0) ? p4.x : (j == 1) ? p4.y : (j == 2) ? p4.z : p4.w;
#pragma unroll
      for (int k = 0; k < NC; ++k) {
        const float m = (tc == k) ? 1.0f : 0.0f;
        S[k] = fmaf(m, pv, S[k]);
        if (do_cnt) cnt[k] += m;
      }
    }
  }

#pragma unroll
  for (int k = 0; k < NC; ++k) {
    S[k] = wave_reduce(S[k]);
    if (do_cnt) cnt[k] = wave_reduce(cnt[k]);
  }
  __shared__ float red[TPB / 64][2 * NC];
  const int w = tid >> 6, lane = tid & 63;
  if (lane == 0) {
#pragma unroll
    for (int k = 0; k < NC; ++k) { red[w][k] = S[k]; red[w][NC + k] = cnt[k]; }
  }
  __syncthreads();
  if (tid < NC) {
    float v = 0.0f;
#pragma unroll
    for (int ww = 0; ww < TPB / 64; ++ww) v += red[ww][tid];
    atomicAdd(&ws[b * NC * NC + ci * NC + tid], v);
  } else if (do_cnt && tid >= NC && tid < 2 * NC) {
    const int k = tid - NC;
    float v = 0.0f;
#pragma unroll
    for (int ww = 0; ww < TPB / 64; ++ww) v += red[ww][NC + k];
    atomicAdd(&ws[N_BASE + b * NC + k], v);
  }
}

// Streaming logsumexp: no target needed (NLL term = trace(S)). Runs after
// s_kernel so pred is L3-resident (144MB < 256MB). ~30 live VGPR; 8
// independent channel loads per group give per-thread MLP.
__global__ __launch_bounds__(TPB, 4)
void lse_kernel(const float* __restrict__ pred, float* __restrict__ ws,
                float* __restrict__ out) {
  const int b = blockIdx.y;
  const int tid = threadIdx.x;
  const float* predb = pred + (size_t)b * NC * HW;

  float ce = 0.0f;
  for (int g = blockIdx.x * TPB + tid; g < GRP; g += PCH_L * TPB) {
    float4 es = {0.0f, 0.0f, 0.0f, 0.0f};
#pragma unroll
    for (int c = 0; c < NC; ++c) {
      const float4 p4 = ((const float4*)(predb + (size_t)c * HW))[g];
      es.x += __expf(p4.x);
      es.y += __expf(p4.y);
      es.z += __expf(p4.z);
      es.w += __expf(p4.w);
    }
    ce += __logf(es.x) + __logf(es.y) + __logf(es.z) + __logf(es.w);
  }

  ce = wave_reduce(ce);
  __shared__ float red[TPB / 64];
  const int w = tid >> 6, lane = tid & 63;
  if (lane == 0) red[w] = ce;
  __syncthreads();
  if (tid == 0) {
    float v = 0.0f;
#pragma unroll
    for (int ww = 0; ww < TPB / 64; ++ww) v += red[ww];
    atomicAdd(&ws[LSE_IDX], v);
  }

  // ---- last-block-done finalize ----
  __shared__ int is_last;
  __syncthreads();
  if (tid == 0) {
    __threadfence();
    unsigned prev = atomicAdd((unsigned*)&ws[CTR_IDX], 1u);
    is_last = (prev == (unsigned)(NBLK_L - 1)) ? 1 : 0;
  }
  __syncthreads();
  if (!is_last) return;

  // S/n from previous dispatch (visible at kernel boundary); lse partials
  // from this kernel guaranteed by the counter protocol. atomicAdd(p,0)
  // reads bypass any stale per-XCD L2 line.
  float acc = 0.0f, tr = 0.0f;
  for (int idx = tid; idx < NB * NC * NC; idx += TPB) {
    const int bb = idx >> 6, ci = (idx >> 3) & 7, ck = idx & 7;
    const float Sval = atomicAdd(&ws[idx], 0.0f);
    if (ci == ck) { tr += Sval; continue; }
    const float n_ck = atomicAdd(&ws[N_BASE + bb * NC + ck], 0.0f);
    const float n_ci = atomicAdd(&ws[N_BASE + bb * NC + ci], 0.0f);
    const float Sii = atomicAdd(&ws[bb * NC * NC + ci * NC + ci], 0.0f);
    acc += logf(0.5f + 0.5f * (Sii / n_ci - Sval / n_ck));
  }
  acc = wave_reduce(acc);
  tr = wave_reduce(tr);
  __shared__ float r2[TPB / 64][2];
  if (lane == 0) { r2[w][0] = acc; r2[w][1] = tr; }
  __syncthreads();
  if (tid == 0) {
    float a = 0.0f, t = 0.0f;
#pragma unroll
    for (int ww = 0; ww < TPB / 64; ++ww) { a += r2[ww][0]; t += r2[ww][1]; }
    const float jl = -a / (float)NB;
    const float lse = atomicAdd(&ws[LSE_IDX], 0.0f);
    out[0] = jl + (lse - t) / ((float)NB * (float)HW);
  }
}

extern "C" void kernel_launch(void* const* d_in, const int* in_sizes, int n_in,
                              void* d_out, int out_size, void* d_ws, size_t ws_size,
                              hipStream_t stream) {
  const float* pred = (const float*)d_in[0];
  const int* target = (const int*)d_in[1];
  float* out = (float*)d_out;
  float* ws = (float*)d_ws;

  hipMemsetAsync(ws, 0, WS_FLOATS * sizeof(float), stream);
  s_kernel<<<dim3(PCH_S, NC, NB), TPB, 0, stream>>>(pred, target, ws);
  lse_kernel<<<dim3(PCH_L, NB), TPB, 0, stream>>>(pred, ws, out);
}

// Round 8
// 254.262 us; speedup vs baseline: 1.1087x; 1.0746x over previous
//
#include <hip/hip_runtime.h>

#define NB 16
#define NC 8
#define HW (512 * 512)
#define GRP (HW / 4)          // 65536 float4-groups per plane
#define TPB 256
#define BPB 64                // blocks per batch
#define NBLOCKS (BPB * NB)    // 1024 = exactly 4 blocks/CU at 4 waves/SIMD (VGPR<=128)
#define GSTEP (BPB * (TPB / 4))   // 4096 groups covered per batch per iteration
#define ITERS (GRP / GSTEP)       // 16

// ws (floats): [0,1024) S[b][ci][ck]; [1024,1152) n[b][k]; [1152] lse_sum; [1153] ctr
#define N_BASE (NB * NC * NC)
#define CE_IDX (N_BASE + NB * NC)
#define CTR_IDX (CE_IDX + 1)
#define WS_FLOATS (CTR_IDX + 1)

// One pass over pred+target (145MB). 4-lane group owns one float4 pixel-group;
// lane sub=tid&3 owns channels {2sub,2sub+1}. Per-thread acc = 24 regs, cap 128
// via __launch_bounds__(256,4) — the only regime that has never spilled
// (r3: cap128+S[64] spilled; r5: VGPR=128 pipeline strangled; r7: cap64 spilled).
__global__ __launch_bounds__(TPB, 4)
void jce_fused(const float* __restrict__ pred, const int* __restrict__ target,
               float* __restrict__ ws, float* __restrict__ out) {
  const int b = blockIdx.y;
  const int tid = threadIdx.x;
  const int sub = tid & 3;    // channel pair index, also claimed pixel component
  const int grp = tid >> 2;   // 0..63: group slot within block
  const float* predb = pred + (size_t)b * NC * HW;
  const float4* pl0 = (const float4*)(predb + (size_t)(2 * sub) * HW);
  const float4* pl1 = (const float4*)(predb + (size_t)(2 * sub + 1) * HW);
  const int4* tgt = (const int4*)(target + (size_t)b * HW);

  float S0[NC], S1[NC], cnt[NC];
  float ce = 0.0f;
#pragma unroll
  for (int k = 0; k < NC; ++k) { S0[k] = 0.0f; S1[k] = 0.0f; cnt[k] = 0.0f; }

  for (int it = 0; it < ITERS; ++it) {
    const int gg = blockIdx.x * (TPB / 4) + grp + it * GSTEP;
    const int4 t4 = tgt[gg];        // 4-way broadcast within the lane group
    const float4 pA = pl0[gg];      // own channel pair, 256B/plane-segment/wave
    const float4 pB = pl1[gg];

    // partial exp-sums (2 channels) per pixel component
    float e0 = __expf(pA.x) + __expf(pB.x);
    float e1 = __expf(pA.y) + __expf(pB.y);
    float e2 = __expf(pA.z) + __expf(pB.z);
    float e3 = __expf(pA.w) + __expf(pB.w);
    // 4-lane-group butterfly: assemble full sum over 8 channels, no barrier
    e0 += __shfl_xor(e0, 1); e0 += __shfl_xor(e0, 2);
    e1 += __shfl_xor(e1, 1); e1 += __shfl_xor(e1, 2);
    e2 += __shfl_xor(e2, 1); e2 += __shfl_xor(e2, 2);
    e3 += __shfl_xor(e3, 1); e3 += __shfl_xor(e3, 2);

    // lane claims pixel component == sub: lse + target histogram (once/pixel)
    const float es = (sub == 0) ? e0 : (sub == 1) ? e1 : (sub == 2) ? e2 : e3;
    ce += __logf(es);
    const int tcl = (sub == 0) ? t4.x : (sub == 1) ? t4.y : (sub == 2) ? t4.z : t4.w;
#pragma unroll
    for (int k = 0; k < NC; ++k) cnt[k] += (tcl == k) ? 1.0f : 0.0f;

    // S rows for own 2 channels, all 4 pixels of the group
#define UPD(TC, VA, VB)                                                  \
    do {                                                                 \
      const int tc = (TC); const float va = (VA), vb = (VB);             \
      _Pragma("unroll") for (int k = 0; k < NC; ++k) {                   \
        const float m = (tc == k) ? 1.0f : 0.0f;                         \
        S0[k] = fmaf(m, va, S0[k]);                                      \
        S1[k] = fmaf(m, vb, S1[k]);                                      \
      }                                                                  \
    } while (0)
    UPD(t4.x, pA.x, pB.x);
    UPD(t4.y, pA.y, pB.y);
    UPD(t4.z, pA.z, pB.z);
    UPD(t4.w, pA.w, pB.w);
#undef UPD
  }

  // ---- wave reductions ----
  // S: reduce across the 16 lanes sharing the same sub (masks 4..32)
#pragma unroll
  for (int k = 0; k < NC; ++k) {
#pragma unroll
    for (int m = 4; m <= 32; m <<= 1) {
      S0[k] += __shfl_xor(S0[k], m);
      S1[k] += __shfl_xor(S1[k], m);
    }
  }
  // cnt, ce: full 64-lane butterfly
#pragma unroll
  for (int k = 0; k < NC; ++k) cnt[k] = [] (float v) { return v; }(cnt[k]);
#pragma unroll
  for (int m = 1; m <= 32; m <<= 1) {
#pragma unroll
    for (int k = 0; k < NC; ++k) cnt[k] += __shfl_xor(cnt[k], m);
    ce += __shfl_xor(ce, m);
  }

  // ---- cross-wave via LDS ----
  __shared__ float redS[TPB / 64][4][2 * NC];  // [wave][sub][channel-of-pair*8+k]
  __shared__ float redC[TPB / 64][NC];
  __shared__ float redE[TPB / 64];
  const int w = tid >> 6, lane = tid & 63;
  if (lane < 4) {
#pragma unroll
    for (int k = 0; k < NC; ++k) {
      redS[w][lane][k] = S0[k];
      redS[w][lane][NC + k] = S1[k];
    }
  }
  if (lane == 0) {
#pragma unroll
    for (int k = 0; k < NC; ++k) redC[w][k] = cnt[k];
    redE[w] = ce;
  }
  __syncthreads();
  if (tid < 64) {
    const int sb = tid >> 4, r = (tid >> 3) & 1, k = tid & 7;
    float v = 0.0f;
#pragma unroll
    for (int ww = 0; ww < TPB / 64; ++ww) v += redS[ww][sb][r * NC + k];
    atomicAdd(&ws[b * NC * NC + (2 * sb + r) * NC + k], v);
  } else if (tid < 64 + NC) {
    const int k = tid - 64;
    float v = 0.0f;
#pragma unroll
    for (int ww = 0; ww < TPB / 64; ++ww) v += redC[ww][k];
    atomicAdd(&ws[N_BASE + b * NC + k], v);
  } else if (tid == 64 + NC) {
    float v = 0.0f;
#pragma unroll
    for (int ww = 0; ww < TPB / 64; ++ww) v += redE[ww];
    atomicAdd(&ws[CE_IDX], v);
  }

  // ---- last-block-done finalize ----
  __shared__ int is_last;
  __syncthreads();
  if (tid == 0) {
    __threadfence();
    unsigned prev = atomicAdd((unsigned*)&ws[CTR_IDX], 1u);
    is_last = (prev == (unsigned)(NBLOCKS - 1)) ? 1 : 0;
  }
  __syncthreads();
  if (!is_last) return;

  // atomicAdd(p, 0.0f) reads: device-coherent across per-XCD L2s.
  float acc = 0.0f, tr = 0.0f;
  for (int idx = tid; idx < NB * NC * NC; idx += TPB) {
    const int bb = idx >> 6, ci = (idx >> 3) & 7, ck = idx & 7;
    const float Sval = atomicAdd(&ws[idx], 0.0f);
    if (ci == ck) { tr += Sval; continue; }
    const float n_ck = atomicAdd(&ws[N_BASE + bb * NC + ck], 0.0f);
    const float n_ci = atomicAdd(&ws[N_BASE + bb * NC + ci], 0.0f);
    const float Sii = atomicAdd(&ws[bb * NC * NC + ci * NC + ci], 0.0f);
    acc += logf(0.5f + 0.5f * (Sii / n_ci - Sval / n_ck));
  }
#pragma unroll
  for (int m = 1; m <= 32; m <<= 1) {
    acc += __shfl_xor(acc, m);
    tr += __shfl_xor(tr, m);
  }
  __shared__ float r2[TPB / 64][2];
  if (lane == 0) { r2[w][0] = acc; r2[w][1] = tr; }
  __syncthreads();
  if (tid == 0) {
    float a = 0.0f, t = 0.0f;
#pragma unroll
    for (int ww = 0; ww < TPB / 64; ++ww) { a += r2[ww][0]; t += r2[ww][1]; }
    const float jl = -a / (float)NB;
    const float lse = atomicAdd(&ws[CE_IDX], 0.0f);
    out[0] = jl + (lse - t) / ((float)NB * (float)HW);
  }
}

extern "C" void kernel_launch(void* const* d_in, const int* in_sizes, int n_in,
                              void* d_out, int out_size, void* d_ws, size_t ws_size,
                              hipStream_t stream) {
  const float* pred = (const float*)d_in[0];
  const int* target = (const int*)d_in[1];
  float* out = (float*)d_out;
  float* ws = (float*)d_ws;

  hipMemsetAsync(ws, 0, WS_FLOATS * sizeof(float), stream);
  dim3 grid(BPB, NB);
  jce_fused<<<grid, TPB, 0, stream>>>(pred, target, ws, out);
}